// Round 3
// baseline (2767.979 us; speedup 1.0000x reference)
//
#include <hip/hip_runtime.h>
#include <hip/hip_bf16.h>

// GCN autoencoder: 4 layers sharing one COO adjacency (N=100000, E=3200000).
// spmm(adj, d1 @ W4) == (adj @ d1) @ W4  -> all spmms run at D<=32.
// Round 3: fine CSR scatter had 8x HBM write amplification (198MB for 25.6MB).
// Replace with coarse 128-row buckets (LDS-binned grouped scatter, ~1.2x amp)
// + bucket-per-block SpMM accumulating in LDS via ds_add_f32.

#define N_NODES 100000
#define N_EDGES 3200000
#define RPB_LOG 7
#define RPB (1 << RPB_LOG)                       // 128 rows per bucket
#define NB ((N_NODES + RPB - 1) / RPB)           // 782 buckets
#define CHUNK 16384
#define NCHUNK ((N_EDGES + CHUNK - 1) / CHUNK)   // 196 blocks

// ---------------------------------------------------------------------------
// mm1: h1[N,32] = x[N,512] @ W1[512,32]
// ---------------------------------------------------------------------------
__global__ __launch_bounds__(256) void mm1_kernel(
    const float* __restrict__ x, const float* __restrict__ W,
    float* __restrict__ out) {
  __shared__ float xt[256][68];
  const int t = threadIdx.x;
  const int r0 = blockIdx.x * 256;

  float acc[32];
#pragma unroll
  for (int j = 0; j < 32; ++j) acc[j] = 0.f;

  for (int kc = 0; kc < 512; kc += 64) {
    __syncthreads();
#pragma unroll
    for (int m = 0; m < 16; ++m) {
      int l = m * 1024 + t * 4;
      int rr = l >> 6, cc = l & 63;
      int gr = r0 + rr;
      float4 v = make_float4(0.f, 0.f, 0.f, 0.f);
      if (gr < N_NODES) v = *(const float4*)(x + (size_t)gr * 512 + kc + cc);
      *(float4*)&xt[rr][cc] = v;
    }
    __syncthreads();

    for (int k = 0; k < 64; k += 4) {
      float4 xv = *(const float4*)&xt[t][k];
#pragma unroll
      for (int u = 0; u < 4; ++u) {
        float xs = (u == 0) ? xv.x : (u == 1) ? xv.y : (u == 2) ? xv.z : xv.w;
        const float* wrow = W + (kc + k + u) * 32;  // wave-uniform -> s_load
#pragma unroll
        for (int j = 0; j < 32; ++j) acc[j] += xs * wrow[j];
      }
    }
  }

  const int r = r0 + t;
  if (r < N_NODES) {
#pragma unroll
    for (int j = 0; j < 32; j += 4)
      *(float4*)(out + (size_t)r * 32 + j) =
          make_float4(acc[j], acc[j + 1], acc[j + 2], acc[j + 3]);
  }
}

// ---------------------------------------------------------------------------
// Coarse bucket build: histogram -> scan(782) -> LDS-binned grouped scatter
// ---------------------------------------------------------------------------
__global__ __launch_bounds__(256) void hist_coarse_kernel(
    const int* __restrict__ rows, int* __restrict__ gcnt) {
  __shared__ int h[NB];
  for (int i = threadIdx.x; i < NB; i += 256) h[i] = 0;
  __syncthreads();
  int c0 = blockIdx.x * CHUNK;
  int c1 = min(c0 + CHUNK, N_EDGES);
  for (int e = c0 + threadIdx.x; e < c1; e += 256)
    atomicAdd(&h[rows[e] >> RPB_LOG], 1);
  __syncthreads();
  for (int i = threadIdx.x; i < NB; i += 256)
    if (h[i]) atomicAdd(&gcnt[i], h[i]);
}

__global__ __launch_bounds__(1024) void scan_kernel(
    const int* __restrict__ gcnt, int* __restrict__ bstart,
    int* __restrict__ gcur) {
  __shared__ int s[1024];
  int t = threadIdx.x;
  s[t] = (t < NB) ? gcnt[t] : 0;
  __syncthreads();
  for (int off = 1; off < 1024; off <<= 1) {
    int v = (t >= off) ? s[t - off] : 0;
    __syncthreads();
    s[t] += v;
    __syncthreads();
  }
  if (t < NB) {
    int excl = (t == 0) ? 0 : s[t - 1];
    bstart[t] = excl;
    gcur[t] = excl;
  }
  if (t == 0) bstart[NB] = N_EDGES;
}

// Per (block,bucket) groups (~21 edges = 168B) are contiguous -> HBM sectors
// mostly full. Payload: packed (row_local<<17 | col, val_bits).
__global__ __launch_bounds__(256) void scatter_bucket_kernel(
    const int* __restrict__ rows, const int* __restrict__ cols,
    const float* __restrict__ vals, int* __restrict__ gcur,
    int2* __restrict__ colval) {
  __shared__ int lcnt[NB];
  __shared__ int lbase[NB];
  for (int i = threadIdx.x; i < NB; i += 256) lcnt[i] = 0;
  __syncthreads();
  int c0 = blockIdx.x * CHUNK;
  int c1 = min(c0 + CHUNK, N_EDGES);
  for (int e = c0 + threadIdx.x; e < c1; e += 256)
    atomicAdd(&lcnt[rows[e] >> RPB_LOG], 1);
  __syncthreads();
  for (int i = threadIdx.x; i < NB; i += 256) {
    int c = lcnt[i];
    lbase[i] = c ? atomicAdd(&gcur[i], c) : 0;
    lcnt[i] = 0;  // reuse as rank counter
  }
  __syncthreads();
  for (int e = c0 + threadIdx.x; e < c1; e += 256) {
    int r = rows[e];
    int b = r >> RPB_LOG;
    int rank = atomicAdd(&lcnt[b], 1);
    int rl = r & (RPB - 1);
    colval[lbase[b] + rank] = make_int2((rl << 17) | cols[e], __float_as_int(vals[e]));
  }
}

// ---------------------------------------------------------------------------
// Bucketed SpMM: block = one 128-row bucket. LDS fp32 accumulator with +1
// stride (bank = (row+col)%32, random rows -> spread). D/4 lanes per edge
// gather one dense row (128B / 64B). Output: dense coalesced burst.
// ---------------------------------------------------------------------------
template <int D>
__global__ __launch_bounds__(256) void spmm_bucket_kernel(
    const int* __restrict__ bstart, const int2* __restrict__ colval,
    const float* __restrict__ in, float* __restrict__ out) {
  constexpr int STRIDE = D + 1;   // 33 / 17
  constexpr int L = D / 4;        // lanes per edge: 8 / 4
  constexpr int SLOTS = 256 / L;  // edges in flight: 32 / 64
  __shared__ float acc[RPB * STRIDE];
  const int t = threadIdx.x;
  for (int i = t; i < RPB * STRIDE; i += 256) acc[i] = 0.f;
  __syncthreads();

  const int b = blockIdx.x;
  const int k1 = bstart[b + 1];
  const int c = (t % L) * 4;
  for (int k = bstart[b] + t / L; k < k1; k += SLOTS) {
    int2 cv = colval[k];                 // same addr for L lanes -> broadcast
    int col = cv.x & 0x1FFFF;
    int rl = cv.x >> 17;
    float v = __int_as_float(cv.y);
    float4 g = *(const float4*)(in + (size_t)col * D + c);
    float* a = &acc[rl * STRIDE + c];
    atomicAdd(a + 0, v * g.x);           // ds_add_f32
    atomicAdd(a + 1, v * g.y);
    atomicAdd(a + 2, v * g.z);
    atomicAdd(a + 3, v * g.w);
  }
  __syncthreads();

  const int row0 = b << RPB_LOG;
  const int nrows = min(RPB, N_NODES - row0);
  for (int i = t; i < nrows * D; i += 256) {
    int rr = i / D, cc = i % D;
    out[(size_t)(row0 + rr) * D + cc] = acc[rr * STRIDE + cc];
  }
}

// ---------------------------------------------------------------------------
// mm_small: out[N,JD] = in[N,KD] @ W[KD,JD]
// ---------------------------------------------------------------------------
template <int KD, int JD>
__global__ __launch_bounds__(256) void mm_small_kernel(
    const float* __restrict__ in, const float* __restrict__ W,
    float* __restrict__ out) {
  int r = blockIdx.x * 256 + threadIdx.x;
  if (r >= N_NODES) return;
  float xr[KD];
#pragma unroll
  for (int k = 0; k < KD; k += 4)
    *(float4*)&xr[k] = *(const float4*)(in + (size_t)r * KD + k);
  float acc[JD];
#pragma unroll
  for (int j = 0; j < JD; ++j) acc[j] = 0.f;
#pragma unroll
  for (int k = 0; k < KD; ++k) {
#pragma unroll
    for (int j = 0; j < JD; ++j) acc[j] += xr[k] * W[k * JD + j];
  }
#pragma unroll
  for (int j = 0; j < JD; j += 4)
    *(float4*)(out + (size_t)r * JD + j) = *(float4*)&acc[j];
}

// ---------------------------------------------------------------------------
// mm4: out[N,512] = s4[N,32] @ W4[32,512]
// ---------------------------------------------------------------------------
__global__ __launch_bounds__(512) void mm4_kernel(
    const float* __restrict__ s4, const float* __restrict__ W,
    float* __restrict__ out, int rows_per_block) {
  const int j = threadIdx.x;
  float w[32];
#pragma unroll
  for (int k = 0; k < 32; ++k) w[k] = W[k * 512 + j];
  int r0 = blockIdx.x * rows_per_block;
  int r1 = r0 + rows_per_block;
  if (r1 > N_NODES) r1 = N_NODES;
  for (int r = r0; r < r1; ++r) {
    const float* srow = s4 + (size_t)r * 32;  // uniform -> scalar loads
    float a0 = 0.f, a1 = 0.f, a2 = 0.f, a3 = 0.f;
#pragma unroll
    for (int k = 0; k < 32; k += 4) {
      a0 += srow[k + 0] * w[k + 0];
      a1 += srow[k + 1] * w[k + 1];
      a2 += srow[k + 2] * w[k + 2];
      a3 += srow[k + 3] * w[k + 3];
    }
    out[(size_t)r * 512 + j] = (a0 + a1) + (a2 + a3);
  }
}

// ---------------------------------------------------------------------------
extern "C" void kernel_launch(void* const* d_in, const int* in_sizes, int n_in,
                              void* d_out, int out_size, void* d_ws, size_t ws_size,
                              hipStream_t stream) {
  const float* x     = (const float*)d_in[0];
  const int*   arows = (const int*)d_in[1];
  const int*   acols = (const int*)d_in[2];
  const float* avals = (const float*)d_in[3];
  const float* W1    = (const float*)d_in[4];  // [512,32]
  const float* W2    = (const float*)d_in[5];  // [32,16]
  const float* W3    = (const float*)d_in[6];  // [16,32]
  const float* W4    = (const float*)d_in[7];  // [32,512]

  float* out = (float*)d_out;
  float* dec = out;                            // [N,512] written LAST (mm4)
  float* enc = out + (size_t)N_NODES * 512;    // [N,16]

  float* A = (float*)d_ws;                     // [N,32]
  float* B = A + (size_t)N_NODES * 32;         // [N,32]

  // Bucket scratch in the decoded2 region of d_out (only mm4, the final
  // kernel, writes it — and fully overwrites). 25.7 MB << 204.8 MB.
  int2* colval = (int2*)dec;                   // [E]
  int*  gcnt   = (int*)(colval + N_EDGES);     // [NB]
  int*  bstart = gcnt + NB;                    // [NB+1]
  int*  gcur   = bstart + NB + 1;              // [NB]

  const int mmGrid = (N_NODES + 255) / 256;

  // ---- build coarse buckets (once; reused by all 4 SpMMs) ----
  hipMemsetAsync(gcnt, 0, NB * sizeof(int), stream);
  hist_coarse_kernel<<<NCHUNK, 256, 0, stream>>>(arows, gcnt);
  scan_kernel<<<1, 1024, 0, stream>>>(gcnt, bstart, gcur);
  scatter_bucket_kernel<<<NCHUNK, 256, 0, stream>>>(arows, acols, avals, gcur, colval);

  // ---- pipeline ----
  mm1_kernel<<<mmGrid, 256, 0, stream>>>(x, W1, A);                         // h1 -> A
  spmm_bucket_kernel<32><<<NB, 256, 0, stream>>>(bstart, colval, A, B);     // e1 -> B
  mm_small_kernel<32, 16><<<mmGrid, 256, 0, stream>>>(B, W2, A);            // h2 -> A
  spmm_bucket_kernel<16><<<NB, 256, 0, stream>>>(bstart, colval, A, enc);   // e2 -> enc
  mm_small_kernel<16, 32><<<mmGrid, 256, 0, stream>>>(enc, W3, B);          // h3 -> B
  spmm_bucket_kernel<32><<<NB, 256, 0, stream>>>(bstart, colval, B, A);     // d1 -> A
  spmm_bucket_kernel<32><<<NB, 256, 0, stream>>>(bstart, colval, A, B);     // s4 -> B
  mm4_kernel<<<(N_NODES + 63) / 64, 512, 0, stream>>>(B, W4, dec, 64);      // dec
}

// Round 4
// 664.937 us; speedup vs baseline: 4.1628x; 4.1628x over previous
//
#include <hip/hip_runtime.h>
#include <hip/hip_bf16.h>

// GCN autoencoder: 4 layers sharing one COO adjacency (N=100000, E=3200000).
// spmm(adj, d1 @ W4) == (adj @ d1) @ W4  -> all spmms run at D<=32.
// Round 4: two-phase sort (coarse 128-row buckets w/ grouped writes -> per-
// bucket counting-sort refine to exact CSR; all write-amp-free), then
// round-2's high-occupancy row-parallel CSR SpMM (4-way unrolled gathers).

#define N_NODES 100000
#define N_EDGES 3200000
#define RPB_LOG 7
#define RPB (1 << RPB_LOG)                       // 128 rows per bucket
#define NB ((N_NODES + RPB - 1) / RPB)           // 782 buckets
#define CHUNK 16384
#define NCHUNK ((N_EDGES + CHUNK - 1) / CHUNK)   // 196 blocks

// ---------------------------------------------------------------------------
// mm1: h1[N,32] = x[N,512] @ W1[512,32]
// ---------------------------------------------------------------------------
__global__ __launch_bounds__(256) void mm1_kernel(
    const float* __restrict__ x, const float* __restrict__ W,
    float* __restrict__ out) {
  __shared__ float xt[256][68];
  const int t = threadIdx.x;
  const int r0 = blockIdx.x * 256;

  float acc[32];
#pragma unroll
  for (int j = 0; j < 32; ++j) acc[j] = 0.f;

  for (int kc = 0; kc < 512; kc += 64) {
    __syncthreads();
#pragma unroll
    for (int m = 0; m < 16; ++m) {
      int l = m * 1024 + t * 4;
      int rr = l >> 6, cc = l & 63;
      int gr = r0 + rr;
      float4 v = make_float4(0.f, 0.f, 0.f, 0.f);
      if (gr < N_NODES) v = *(const float4*)(x + (size_t)gr * 512 + kc + cc);
      *(float4*)&xt[rr][cc] = v;
    }
    __syncthreads();

    for (int k = 0; k < 64; k += 4) {
      float4 xv = *(const float4*)&xt[t][k];
#pragma unroll
      for (int u = 0; u < 4; ++u) {
        float xs = (u == 0) ? xv.x : (u == 1) ? xv.y : (u == 2) ? xv.z : xv.w;
        const float* wrow = W + (kc + k + u) * 32;  // wave-uniform -> s_load
#pragma unroll
        for (int j = 0; j < 32; ++j) acc[j] += xs * wrow[j];
      }
    }
  }

  const int r = r0 + t;
  if (r < N_NODES) {
#pragma unroll
    for (int j = 0; j < 32; j += 4)
      *(float4*)(out + (size_t)r * 32 + j) =
          make_float4(acc[j], acc[j + 1], acc[j + 2], acc[j + 3]);
  }
}

// ---------------------------------------------------------------------------
// Phase A: coarse bucket sort (grouped writes, ~1.2x amplification)
// ---------------------------------------------------------------------------
__global__ __launch_bounds__(256) void hist_coarse_kernel(
    const int* __restrict__ rows, int* __restrict__ gcnt) {
  __shared__ int h[NB];
  for (int i = threadIdx.x; i < NB; i += 256) h[i] = 0;
  __syncthreads();
  int c0 = blockIdx.x * CHUNK;
  int c1 = min(c0 + CHUNK, N_EDGES);
  for (int e = c0 + threadIdx.x; e < c1; e += 256)
    atomicAdd(&h[rows[e] >> RPB_LOG], 1);
  __syncthreads();
  for (int i = threadIdx.x; i < NB; i += 256)
    if (h[i]) atomicAdd(&gcnt[i], h[i]);
}

__global__ __launch_bounds__(1024) void scan_kernel(
    const int* __restrict__ gcnt, int* __restrict__ bstart,
    int* __restrict__ gcur, int* __restrict__ row_ptr) {
  __shared__ int s[1024];
  int t = threadIdx.x;
  s[t] = (t < NB) ? gcnt[t] : 0;
  __syncthreads();
  for (int off = 1; off < 1024; off <<= 1) {
    int v = (t >= off) ? s[t - off] : 0;
    __syncthreads();
    s[t] += v;
    __syncthreads();
  }
  if (t < NB) {
    int excl = (t == 0) ? 0 : s[t - 1];
    bstart[t] = excl;
    gcur[t] = excl;
  }
  if (t == 0) { bstart[NB] = N_EDGES; row_ptr[N_NODES] = N_EDGES; }
}

// payload: (row_local<<17 | col, val_bits); per-(block,bucket) groups ~21
// edges = 168B contiguous -> HBM sectors mostly full.
__global__ __launch_bounds__(256) void scatter_bucket_kernel(
    const int* __restrict__ rows, const int* __restrict__ cols,
    const float* __restrict__ vals, int* __restrict__ gcur,
    int2* __restrict__ colval) {
  __shared__ int lcnt[NB];
  __shared__ int lbase[NB];
  for (int i = threadIdx.x; i < NB; i += 256) lcnt[i] = 0;
  __syncthreads();
  int c0 = blockIdx.x * CHUNK;
  int c1 = min(c0 + CHUNK, N_EDGES);
  for (int e = c0 + threadIdx.x; e < c1; e += 256)
    atomicAdd(&lcnt[rows[e] >> RPB_LOG], 1);
  __syncthreads();
  for (int i = threadIdx.x; i < NB; i += 256) {
    int c = lcnt[i];
    lbase[i] = c ? atomicAdd(&gcur[i], c) : 0;
    lcnt[i] = 0;  // reuse as rank counter
  }
  __syncthreads();
  for (int e = c0 + threadIdx.x; e < c1; e += 256) {
    int r = rows[e];
    int b = r >> RPB_LOG;
    int rank = atomicAdd(&lcnt[b], 1);
    int rl = r & (RPB - 1);
    colval[lbase[b] + rank] = make_int2((rl << 17) | cols[e], __float_as_int(vals[e]));
  }
}

// ---------------------------------------------------------------------------
// Phase B: per-bucket counting sort -> exact CSR + row_ptr.
// Reads contiguous; writes random only within the bucket's ~33KB window
// (L2-resident, lines fill before eviction -> no write amplification).
// ---------------------------------------------------------------------------
__global__ __launch_bounds__(256) void refine_kernel(
    const int* __restrict__ bstart, const int2* __restrict__ cv_in,
    int2* __restrict__ cv_out, int* __restrict__ row_ptr) {
  __shared__ int cnt[RPB];
  __shared__ int base[RPB];
  __shared__ int sc[RPB];
  const int b = blockIdx.x;
  const int t = threadIdx.x;
  const int k0 = bstart[b], k1 = bstart[b + 1];
  if (t < RPB) cnt[t] = 0;
  __syncthreads();
  for (int k = k0 + t; k < k1; k += 256)
    atomicAdd(&cnt[cv_in[k].x >> 17], 1);
  __syncthreads();
  if (t < RPB) sc[t] = cnt[t];
  __syncthreads();
  for (int off = 1; off < RPB; off <<= 1) {
    int v = (t < RPB && t >= off) ? sc[t - off] : 0;
    __syncthreads();
    if (t < RPB) sc[t] += v;
    __syncthreads();
  }
  if (t < RPB) {
    int excl = (t == 0) ? 0 : sc[t - 1];
    base[t] = k0 + excl;
    cnt[t] = 0;  // reuse as cursor
    int gr = (b << RPB_LOG) + t;
    if (gr < N_NODES) row_ptr[gr] = k0 + excl;
  }
  __syncthreads();
  for (int k = k0 + t; k < k1; k += 256) {
    int2 e = cv_in[k];
    int rl = e.x >> 17;
    int pos = base[rl] + atomicAdd(&cnt[rl], 1);
    cv_out[pos] = make_int2(e.x & 0x1FFFF, e.y);
  }
}

// ---------------------------------------------------------------------------
// CSR SpMM: D/4 lanes per row, 4-way unrolled float4 gathers, register
// accumulate, one coalesced non-atomic write. Writes ALL rows.
// ---------------------------------------------------------------------------
template <int D>
__global__ __launch_bounds__(256) void spmm_csr_kernel(
    const int* __restrict__ rp, const int2* __restrict__ colval,
    const float* __restrict__ in, float* __restrict__ out) {
  constexpr int L = D / 4;            // lanes per row
  constexpr int RPBK = 256 / L;       // rows per block
  int t = threadIdx.x;
  int r = blockIdx.x * RPBK + t / L;
  int c = (t % L) * 4;
  if (r >= N_NODES) return;
  int k0 = rp[r], k1 = rp[r + 1];
  float4 acc = make_float4(0.f, 0.f, 0.f, 0.f);
  int k = k0;
  for (; k + 3 < k1; k += 4) {        // 4 independent gathers in flight
    int2 cv0 = colval[k];
    int2 cv1 = colval[k + 1];
    int2 cv2 = colval[k + 2];
    int2 cv3 = colval[k + 3];
    float4 g0 = *(const float4*)(in + (size_t)cv0.x * D + c);
    float4 g1 = *(const float4*)(in + (size_t)cv1.x * D + c);
    float4 g2 = *(const float4*)(in + (size_t)cv2.x * D + c);
    float4 g3 = *(const float4*)(in + (size_t)cv3.x * D + c);
    float v0 = __int_as_float(cv0.y), v1 = __int_as_float(cv1.y);
    float v2 = __int_as_float(cv2.y), v3 = __int_as_float(cv3.y);
    acc.x += v0 * g0.x; acc.y += v0 * g0.y; acc.z += v0 * g0.z; acc.w += v0 * g0.w;
    acc.x += v1 * g1.x; acc.y += v1 * g1.y; acc.z += v1 * g1.z; acc.w += v1 * g1.w;
    acc.x += v2 * g2.x; acc.y += v2 * g2.y; acc.z += v2 * g2.z; acc.w += v2 * g2.w;
    acc.x += v3 * g3.x; acc.y += v3 * g3.y; acc.z += v3 * g3.z; acc.w += v3 * g3.w;
  }
  for (; k < k1; ++k) {
    int2 cv = colval[k];
    float v = __int_as_float(cv.y);
    float4 g = *(const float4*)(in + (size_t)cv.x * D + c);
    acc.x += v * g.x; acc.y += v * g.y; acc.z += v * g.z; acc.w += v * g.w;
  }
  *(float4*)(out + (size_t)r * D + c) = acc;
}

// ---------------------------------------------------------------------------
// mm_small: out[N,JD] = in[N,KD] @ W[KD,JD]
// ---------------------------------------------------------------------------
template <int KD, int JD>
__global__ __launch_bounds__(256) void mm_small_kernel(
    const float* __restrict__ in, const float* __restrict__ W,
    float* __restrict__ out) {
  int r = blockIdx.x * 256 + threadIdx.x;
  if (r >= N_NODES) return;
  float xr[KD];
#pragma unroll
  for (int k = 0; k < KD; k += 4)
    *(float4*)&xr[k] = *(const float4*)(in + (size_t)r * KD + k);
  float acc[JD];
#pragma unroll
  for (int j = 0; j < JD; ++j) acc[j] = 0.f;
#pragma unroll
  for (int k = 0; k < KD; ++k) {
#pragma unroll
    for (int j = 0; j < JD; ++j) acc[j] += xr[k] * W[k * JD + j];
  }
#pragma unroll
  for (int j = 0; j < JD; j += 4)
    *(float4*)(out + (size_t)r * JD + j) = *(float4*)&acc[j];
}

// ---------------------------------------------------------------------------
// mm4: out[N,512] = s4[N,32] @ W4[32,512]
// ---------------------------------------------------------------------------
__global__ __launch_bounds__(512) void mm4_kernel(
    const float* __restrict__ s4, const float* __restrict__ W,
    float* __restrict__ out, int rows_per_block) {
  const int j = threadIdx.x;
  float w[32];
#pragma unroll
  for (int k = 0; k < 32; ++k) w[k] = W[k * 512 + j];
  int r0 = blockIdx.x * rows_per_block;
  int r1 = r0 + rows_per_block;
  if (r1 > N_NODES) r1 = N_NODES;
  for (int r = r0; r < r1; ++r) {
    const float* srow = s4 + (size_t)r * 32;  // uniform -> scalar loads
    float a0 = 0.f, a1 = 0.f, a2 = 0.f, a3 = 0.f;
#pragma unroll
    for (int k = 0; k < 32; k += 4) {
      a0 += srow[k + 0] * w[k + 0];
      a1 += srow[k + 1] * w[k + 1];
      a2 += srow[k + 2] * w[k + 2];
      a3 += srow[k + 3] * w[k + 3];
    }
    out[(size_t)r * 512 + j] = (a0 + a1) + (a2 + a3);
  }
}

// ---------------------------------------------------------------------------
extern "C" void kernel_launch(void* const* d_in, const int* in_sizes, int n_in,
                              void* d_out, int out_size, void* d_ws, size_t ws_size,
                              hipStream_t stream) {
  const float* x     = (const float*)d_in[0];
  const int*   arows = (const int*)d_in[1];
  const int*   acols = (const int*)d_in[2];
  const float* avals = (const float*)d_in[3];
  const float* W1    = (const float*)d_in[4];  // [512,32]
  const float* W2    = (const float*)d_in[5];  // [32,16]
  const float* W3    = (const float*)d_in[6];  // [16,32]
  const float* W4    = (const float*)d_in[7];  // [32,512]

  float* out = (float*)d_out;
  float* dec = out;                            // [N,512] written LAST (mm4)
  float* enc = out + (size_t)N_NODES * 512;    // [N,16]

  float* A = (float*)d_ws;                     // [N,32]
  float* B = A + (size_t)N_NODES * 32;         // [N,32]

  // Sort scratch in the decoded2 region of d_out (52 MB << 204.8 MB; only
  // mm4 — the final kernel — writes dec, fully overwriting it).
  int2* cv_bkt  = (int2*)dec;                  // [E] bucket-sorted
  int2* cv_csr  = cv_bkt + N_EDGES;            // [E] CSR-sorted
  int*  row_ptr = (int*)(cv_csr + N_EDGES);    // [N+1]
  int*  gcnt    = row_ptr + N_NODES + 1;       // [NB]
  int*  bstart  = gcnt + NB;                   // [NB+1]
  int*  gcur    = bstart + NB + 1;             // [NB]

  const int mmGrid = (N_NODES + 255) / 256;

  // ---- build CSR via two-phase sort (once; reused by all 4 SpMMs) ----
  hipMemsetAsync(gcnt, 0, NB * sizeof(int), stream);
  hist_coarse_kernel<<<NCHUNK, 256, 0, stream>>>(arows, gcnt);
  scan_kernel<<<1, 1024, 0, stream>>>(gcnt, bstart, gcur, row_ptr);
  scatter_bucket_kernel<<<NCHUNK, 256, 0, stream>>>(arows, acols, avals, gcur, cv_bkt);
  refine_kernel<<<NB, 256, 0, stream>>>(bstart, cv_bkt, cv_csr, row_ptr);

  // ---- pipeline ----
  mm1_kernel<<<mmGrid, 256, 0, stream>>>(x, W1, A);                          // h1 -> A
  spmm_csr_kernel<32><<<(N_NODES + 31) / 32, 256, 0, stream>>>(row_ptr, cv_csr, A, B);   // e1 -> B
  mm_small_kernel<32, 16><<<mmGrid, 256, 0, stream>>>(B, W2, A);             // h2 -> A
  spmm_csr_kernel<16><<<(N_NODES + 63) / 64, 256, 0, stream>>>(row_ptr, cv_csr, A, enc); // e2 -> enc
  mm_small_kernel<16, 32><<<mmGrid, 256, 0, stream>>>(enc, W3, B);           // h3 -> B
  spmm_csr_kernel<32><<<(N_NODES + 31) / 32, 256, 0, stream>>>(row_ptr, cv_csr, B, A);   // d1 -> A
  spmm_csr_kernel<32><<<(N_NODES + 31) / 32, 256, 0, stream>>>(row_ptr, cv_csr, A, B);   // s4 -> B
  mm4_kernel<<<(N_NODES + 63) / 64, 512, 0, stream>>>(B, W4, dec, 64);       // dec
}